// Round 17
// baseline (261.897 us; speedup 1.0000x reference)
//
#include <hip/hip_runtime.h>
#include <hip/hip_bf16.h>
#include <stdint.h>

#define NUM_B 4
#define NUM_C 192
#define NUM_C2 384
#define NUM_H 128
#define NUM_W 128
#define NUM_N 16384
#define NHEADS 8
#define CHD 24

#define NKC 128          // K-chunks in dots kernel (R14-proven)
#define PSTRIDE 1280     // partial slots per (kc,bh), 1248 used
#define LROWF 132        // prepack LDS row stride (f32)

typedef float f32x4_t __attribute__((ext_vector_type(4)));
typedef float f32x2_t __attribute__((ext_vector_type(2)));
typedef __bf16 bf16x8_t __attribute__((ext_vector_type(8)));
typedef unsigned short u16x8_t __attribute__((ext_vector_type(8)));
typedef unsigned short u16x4_t __attribute__((ext_vector_type(4)));

__device__ __forceinline__ float bf2f(unsigned short u){
  union { unsigned int i; float f; } v; v.i = ((unsigned int)u) << 16; return v.f;
}
__device__ __forceinline__ unsigned short f2bf(float f){
  union { float f; unsigned int i; } v; v.f = f;
  unsigned int x = v.i;
  x += 0x7fffu + ((x >> 16) & 1u);   // round-to-nearest-even
  return (unsigned short)(x >> 16);
}
__device__ __forceinline__ unsigned short f2bf_n(float f){
  union { __bf16 h; unsigned short u; } cv; cv.h = (__bf16)f; return cv.u;
}

// ---------------------------------------------------------------------------
// Kernel 0: prepack inputs x,y fp32 -> bf16 via LDS transpose (R12-proven),
// MERGED with weight prepack (blockIdx.y == 6; independent outputs -> safe).
// Input layout: [b][nt(128)][s(6)][n(128)][slot(4)][8], slot^((n>>1)&3).
// Weight layout: [br(3)][ot(3)][s(6)][o(128)][slot(4)][8], slot c^((o>>1)&3).
// ---------------------------------------------------------------------------
__global__ __launch_bounds__(256) void prepack_all(
    const float* __restrict__ x, const float* __restrict__ y,
    const float* __restrict__ W0, const float* __restrict__ W1,
    const float* __restrict__ W2,
    unsigned short* __restrict__ xb, unsigned short* __restrict__ yb,
    unsigned short* __restrict__ Wpk)
{
  const int t = threadIdx.x;
  if (blockIdx.y == 6){
    int flat = blockIdx.z * 128 + blockIdx.x;
    if (flat >= 108) return;
    int gtid = flat * 256 + t;           // [0, 27648)
    int br = gtid / 9216;
    int tid = gtid % 9216;
    const float* W = (br == 0) ? W0 : (br == 1) ? W1 : W2;
    unsigned short* o_ = Wpk + (size_t)br * 73728;
    int c = tid & 3;
    int o = (tid >> 2) & 127;
    int s = (tid >> 9) % 6;
    int ot = tid / 3072;
    int sw = c ^ ((o >> 1) & 3);
    const float* src = W + (size_t)(ot * 128 + o) * NUM_C + s * 32 + sw * 8;
    f32x4_t f0 = *(const f32x4_t*)src;
    f32x4_t f1 = *(const f32x4_t*)(src + 4);
    u16x8_t pk;
    pk[0] = f2bf(f0[0]); pk[1] = f2bf(f0[1]); pk[2] = f2bf(f0[2]); pk[3] = f2bf(f0[3]);
    pk[4] = f2bf(f1[0]); pk[5] = f2bf(f1[1]); pk[6] = f2bf(f1[2]); pk[7] = f2bf(f1[3]);
    *(u16x8_t*)(o_ + (size_t)tid * 8) = pk;
    return;
  }
  __shared__ __align__(16) float LX[32 * LROWF];
  __shared__ __align__(16) float LY[32 * LROWF];
  const int nt = blockIdx.x, s = blockIdx.y, b = blockIdx.z;
  const float* px = x + (size_t)b * NUM_C * NUM_N + (size_t)s * 32 * NUM_N + nt * 128;
  const float* py = y + (size_t)b * NUM_C * NUM_N + (size_t)s * 32 * NUM_N + nt * 128;
  #pragma unroll
  for (int i = 0; i < 4; i++){
    int idx = t + 256 * i;
    int k = idx >> 5, n4 = idx & 31;
    f32x4_t vx4 = *(const f32x4_t*)(px + (size_t)k * NUM_N + n4 * 4);
    f32x4_t vy4 = *(const f32x4_t*)(py + (size_t)k * NUM_N + n4 * 4);
    int col = (n4 * 4) ^ ((k >> 3) << 3);
    *(f32x4_t*)(&LX[k * LROWF + col]) = vx4;
    *(f32x4_t*)(&LY[k * LROWF + col]) = vy4;
  }
  __syncthreads();
  size_t obase = ((size_t)(b * 128 + nt) * 6 + s) * 4096;
  #pragma unroll
  for (int i = 0; i < 2; i++){
    int u = t + 256 * i;
    int n = u >> 2, slot = u & 3;
    int c = slot ^ ((n >> 1) & 3);
    int colr = n ^ (c << 3);
    u16x8_t ox, oy;
    #pragma unroll
    for (int kk = 0; kk < 8; kk++){
      ox[kk] = f2bf_n(LX[(c * 8 + kk) * LROWF + colr]);
      oy[kk] = f2bf_n(LY[(c * 8 + kk) * LROWF + colr]);
    }
    *(u16x8_t*)(xb + obase + (size_t)u * 8) = ox;
    *(u16x8_t*)(yb + obase + (size_t)u * 8) = oy;
  }
}

// ---------------------------------------------------------------------------
// Kernel 1: FUSED conv1x1, all 3 branches.  (256,4); XCD swizzle (R9);
// z' fragment-native store (R11).  NEW: prefetch DEPTH-2 register pipeline —
// tile ks+2's loads issue a full iteration before their vmcnt wait (the old
// depth-1 exposed ~500cy/step; blocks were ~95% stalled).  A and B deep
// (2 reg sets, tile t in set (t-1)&1); br0's second tensor shallow to stay
// under the 128-reg / 4-blocks-per-CU cliff (R13).  K-loop fully unrolled
// so all reg indices are compile-time (no scratch).
// ---------------------------------------------------------------------------
__global__ __launch_bounds__(256, 4) void conv1x1_fused(
    const unsigned short* __restrict__ xb, const unsigned short* __restrict__ yb,
    const unsigned short* __restrict__ Wpk,
    const float* __restrict__ b0, const float* __restrict__ b1,
    const float* __restrict__ b2, unsigned short* __restrict__ z3)
{
  __shared__ __align__(16) unsigned short As[2][4096];  // [o(128)][slot(4)][8]
  __shared__ __align__(16) unsigned short Bs[2][4096];  // [n(128)][slot(4)][8]
  const int d = blockIdx.x;
  const int xcd = d & 7;
  const int rest = d >> 3;
  const int j = rest % 9;
  const int m_ = (rest / 9) * 8 + xcd;
  const int br = j / 3;
  const int ot = j % 3;
  const int nt = m_ & 127;
  const int b  = m_ >> 7;
  const int t = threadIdx.x;
  const int lane = t & 63;
  const int wv = t >> 6;
  const int wr = wv >> 1, wc = wv & 1;
  const int n0 = nt * 128;

  const unsigned short* Bp0 = (br == 2) ? yb : xb;
  const unsigned short* Bp1 = yb;                    // only used when br==0
  const int add2 = (br == 0);
  const unsigned short* Wb = Wpk + (size_t)br * 73728;
  const float* bias = (br == 0) ? b0 : (br == 1) ? b1 : b2;
  unsigned short* zout = z3 + (size_t)br * NUM_B * NUM_C2 * NUM_N;

  f32x4_t acc[4][4];
  const f32x4_t zz = {0.f, 0.f, 0.f, 0.f};
  #pragma unroll
  for (int m = 0; m < 4; m++)
    #pragma unroll
    for (int nf = 0; nf < 4; nf++) acc[m][nf] = zz;

  u16x8_t areg[2][2], breg[2][2], breg2[2];

  auto loadA_s = [&](int ks, int s){
    const u16x8_t* gp = (const u16x8_t*)(Wb + (size_t)(ot * 6 + ks) * 4096);
    areg[s][0] = gp[t];
    areg[s][1] = gp[t + 256];
  };
  auto loadB_s = [&](int ks, int s){
    const u16x8_t* gp = (const u16x8_t*)(Bp0 + ((size_t)(b * 128 + nt) * 6 + ks) * 4096);
    breg[s][0] = gp[t];
    breg[s][1] = gp[t + 256];
  };
  auto loadB2 = [&](int ks){
    if (add2){
      const u16x8_t* gp2 = (const u16x8_t*)(Bp1 + ((size_t)(b * 128 + nt) * 6 + ks) * 4096);
      breg2[0] = gp2[t];
      breg2[1] = gp2[t + 256];
    }
  };
  auto writeA_s = [&](int s, int buf){
    *(u16x8_t*)(&As[buf][(size_t)t * 8]) = areg[s][0];
    *(u16x8_t*)(&As[buf][(size_t)(t + 256) * 8]) = areg[s][1];
  };
  auto writeB_s = [&](int s, int buf){
    if (!add2){
      *(u16x8_t*)(&Bs[buf][(size_t)t * 8]) = breg[s][0];
      *(u16x8_t*)(&Bs[buf][(size_t)(t + 256) * 8]) = breg[s][1];
    } else {
      #pragma unroll
      for (int i = 0; i < 2; i++){
        u16x8_t r;
        #pragma unroll
        for (int jj = 0; jj < 8; jj++)
          r[jj] = f2bf_n(bf2f(breg[s][i][jj]) + bf2f(breg2[i][jj]));
        *(u16x8_t*)(&Bs[buf][(size_t)(t + 256 * i) * 8]) = r;
      }
    }
  };

  auto compute = [&](int buf){
    const int rsel = lane & 15;
    const int g = lane >> 4;
    bf16x8_t af[4], bfr[4];
    #pragma unroll
    for (int m = 0; m < 4; m++){
      int r = wr * 64 + m * 16 + rsel;
      int sw = g ^ ((r >> 1) & 3);
      af[m] = *(const bf16x8_t*)(&As[buf][r * 32 + sw * 8]);
    }
    #pragma unroll
    for (int nf = 0; nf < 4; nf++){
      int r = wc * 64 + nf * 16 + rsel;
      int sw = g ^ ((r >> 1) & 3);
      bfr[nf] = *(const bf16x8_t*)(&Bs[buf][r * 32 + sw * 8]);
    }
    #pragma unroll
    for (int m = 0; m < 4; m++)
      #pragma unroll
      for (int nf = 0; nf < 4; nf++)
        acc[m][nf] = __builtin_amdgcn_mfma_f32_16x16x32_bf16(af[m], bfr[nf], acc[m][nf], 0, 0, 0);
  };

  // prologue: tile0 staged immediately; tile1 loaded deep into set0
  loadA_s(0, 0); loadB_s(0, 0); loadB2(0);
  writeA_s(0, 0); writeB_s(0, 0);
  loadA_s(1, 0); loadB_s(1, 0);
  __syncthreads();

  // fully unrolled: tile t lives in set (t-1)&1; iter ks loads tile ks+2
  // into set (ks+1)&1, computes buf ks&1, writes tile ks+1 (set ks&1,
  // breg2 loaded this iter) into buf (ks+1)&1.
  #pragma unroll
  for (int ks = 0; ks < 6; ks++){
    if (ks + 1 <= 5) loadB2(ks + 1);
    if (ks + 2 <= 5){
      loadA_s(ks + 2, (ks + 1) & 1);
      loadB_s(ks + 2, (ks + 1) & 1);
    }
    compute(ks & 1);
    if (ks + 1 <= 5){
      writeA_s(ks & 1, (ks + 1) & 1);
      writeB_s(ks & 1, (ks + 1) & 1);
      __syncthreads();
    }
  }

  // epilogue: fragment-native z' store (R11-proven).
  const int colb = lane & 15;
  const int ob_l = lane >> 4;
  #pragma unroll
  for (int m = 0; m < 4; m++){
    int o_blk = ot * 32 + wr * 16 + m * 4 + ob_l;
    #pragma unroll
    for (int nf = 0; nf < 4; nf++){
      int col = n0 + wc * 64 + nf * 16 + colb;
      u16x4_t pk;
      #pragma unroll
      for (int r = 0; r < 4; r++)
        pk[r] = f2bf_n(acc[m][nf][r] + bias[o_blk * 4 + r]);
      *(u16x4_t*)(zout + (((size_t)b * 96 + o_blk) * NUM_N + col) * 4) = pk;
    }
  }
}

// ---------------------------------------------------------------------------
// Kernel 2: grouped 3x3 conv reading the z' 4-row-interleaved layout.
// ---------------------------------------------------------------------------
__global__ __launch_bounds__(256) void gconv4_dw(
    const unsigned short* __restrict__ zp,
    const float* __restrict__ dww, const float* __restrict__ dwb,
    unsigned short* __restrict__ outq)
{
  const int t = threadIdx.x;
  const int wo = t & 15;
  const int hh = t >> 4;
  const int h = blockIdx.x * 16 + hh;
  const int g2 = blockIdx.y;        // 0..95 = o_blk
  const int b = blockIdx.z;

  float v[4][3][8];
  const unsigned short* src = zp + (size_t)(b * 96 + g2) * NUM_N * 4;
  #pragma unroll
  for (int dy = 0; dy < 3; dy++){
    int row = h + dy - 1;
    if (row >= 0 && row < NUM_H){
      const unsigned short* base = src + (size_t)(row * NUM_W + wo * 8) * 4;
      u16x8_t ch[4];
      #pragma unroll
      for (int q = 0; q < 4; q++) ch[q] = *(const u16x8_t*)(base + q * 8);
      #pragma unroll
      for (int jw = 0; jw < 8; jw++)
        #pragma unroll
        for (int c = 0; c < 4; c++){
          int idx = jw * 4 + c;
          v[c][dy][jw] = bf2f(ch[idx >> 3][idx & 7]);
        }
    } else {
      #pragma unroll
      for (int c = 0; c < 4; c++)
        #pragma unroll
        for (int jw = 0; jw < 8; jw++) v[c][dy][jw] = 0.f;
    }
  }
  float lft[4][3], rgt[4][3];
  #pragma unroll
  for (int c = 0; c < 4; c++)
    #pragma unroll
    for (int dy = 0; dy < 3; dy++){
      float l = __shfl_up(v[c][dy][7], 1u, 64);
      float r = __shfl_down(v[c][dy][0], 1u, 64);
      lft[c][dy] = (wo == 0)  ? 0.f : l;
      rgt[c][dy] = (wo == 15) ? 0.f : r;
    }
  #pragma unroll
  for (int c = 0; c < 4; c++){
    const int oc = g2 * 4 + c;
    const int ci0 = c & 2;
    float wgt[2][9];
    #pragma unroll
    for (int icg = 0; icg < 2; icg++)
      #pragma unroll
      for (int k9 = 0; k9 < 9; k9++)
        wgt[icg][k9] = dww[(size_t)oc * 18 + icg * 9 + k9];
    float bia = dwb[oc];
    u16x8_t st;
    #pragma unroll
    for (int w8 = 0; w8 < 8; w8++){
      float s = bia;
      #pragma unroll
      for (int icg = 0; icg < 2; icg++){
        const int ci = ci0 + icg;
        #pragma unroll
        for (int ky = 0; ky < 3; ky++)
          #pragma unroll
          for (int kx = 0; kx < 3; kx++){
            int wx = w8 + kx - 1;
            float xv = (wx < 0) ? lft[ci][ky] : ((wx > 7) ? rgt[ci][ky] : v[ci][ky][wx]);
            s += wgt[icg][ky * 3 + kx] * xv;
          }
      }
      st[w8] = f2bf(s);
    }
    *(u16x8_t*)(outq + ((size_t)b * NUM_C2 + oc) * NUM_N + h * NUM_W + wo * 8) = st;
  }
}

// ---------------------------------------------------------------------------
// Kernel 3: fused Gram + norms via MFMA.  K split over NKC=128 chunks of 128
// (R14-proven).  Atomic-free plain stores; reduced by reduce_dots.
// ---------------------------------------------------------------------------
__global__ __launch_bounds__(64) void dots_kernel(
    const unsigned short* __restrict__ qkv0, const unsigned short* __restrict__ qkv1,
    const unsigned short* __restrict__ qkv2, float* __restrict__ dpart)
{
  const int lane = threadIdx.x;
  const int kc = blockIdx.x;   // NKC chunks of 128 K-elems
  const int h = blockIdx.y;
  const int b = blockIdx.z;
  const unsigned short* q1 = qkv0 + ((size_t)b * NUM_C2 + h * CHD) * NUM_N;
  const unsigned short* q2 = qkv0 + ((size_t)b * NUM_C2 + NUM_C + h * CHD) * NUM_N;
  const unsigned short* kx = qkv1 + ((size_t)b * NUM_C2 + h * CHD) * NUM_N;
  const unsigned short* ky = qkv2 + ((size_t)b * NUM_C2 + h * CHD) * NUM_N;

  const f32x4_t zz = {0.f, 0.f, 0.f, 0.f};
  f32x4_t d1[2][2], d2[2][2], nrm[4][2];
  #pragma unroll
  for (int i = 0; i < 2; i++)
    #pragma unroll
    for (int j = 0; j < 2; j++){ d1[i][j] = zz; d2[i][j] = zz; }
  #pragma unroll
  for (int tn = 0; tn < 4; tn++){ nrm[tn][0] = zz; nrm[tn][1] = zz; }

  const int row = lane & 15;
  const int kl = (lane >> 4) * 8;
  const int r0 = row;
  const int r1 = (16 + row < CHD) ? (16 + row) : (CHD - 1);   // clamp garbage rows
  #pragma unroll
  for (int ks = 0; ks < 4; ks++){
    const size_t k0 = (size_t)kc * 128 + ks * 32 + kl;
    const size_t off0 = (size_t)r0 * NUM_N + k0;
    const size_t off1 = (size_t)r1 * NUM_N + k0;
    bf16x8_t fq1[2], fq2[2], fkx[2], fky[2];
    fq1[0] = *(const bf16x8_t*)(q1 + off0);  fq1[1] = *(const bf16x8_t*)(q1 + off1);
    fq2[0] = *(const bf16x8_t*)(q2 + off0);  fq2[1] = *(const bf16x8_t*)(q2 + off1);
    fkx[0] = *(const bf16x8_t*)(kx + off0);  fkx[1] = *(const bf16x8_t*)(kx + off1);
    fky[0] = *(const bf16x8_t*)(ky + off0);  fky[1] = *(const bf16x8_t*)(ky + off1);
    #pragma unroll
    for (int i = 0; i < 2; i++)
      #pragma unroll
      for (int j = 0; j < 2; j++){
        d1[i][j] = __builtin_amdgcn_mfma_f32_16x16x32_bf16(fq1[i], fky[j], d1[i][j], 0, 0, 0);
        d2[i][j] = __builtin_amdgcn_mfma_f32_16x16x32_bf16(fq2[i], fkx[j], d2[i][j], 0, 0, 0);
      }
    #pragma unroll
    for (int rg = 0; rg < 2; rg++){
      nrm[0][rg] = __builtin_amdgcn_mfma_f32_16x16x32_bf16(fq1[rg], fq1[rg], nrm[0][rg], 0, 0, 0);
      nrm[1][rg] = __builtin_amdgcn_mfma_f32_16x16x32_bf16(fq2[rg], fq2[rg], nrm[1][rg], 0, 0, 0);
      nrm[2][rg] = __builtin_amdgcn_mfma_f32_16x16x32_bf16(fkx[rg], fkx[rg], nrm[2][rg], 0, 0, 0);
      nrm[3][rg] = __builtin_amdgcn_mfma_f32_16x16x32_bf16(fky[rg], fky[rg], nrm[3][rg], 0, 0, 0);
    }
  }

  float* P = dpart + ((size_t)kc * (NUM_B * NHEADS) + (b * NHEADS + h)) * PSTRIDE;
  const int colb = lane & 15;
  const int rb = (lane >> 4) * 4;
  #pragma unroll
  for (int i = 0; i < 2; i++)
    #pragma unroll
    for (int j = 0; j < 2; j++){
      int cc = j * 16 + colb;
      if (cc < CHD){
        #pragma unroll
        for (int r = 0; r < 4; r++){
          int rr = i * 16 + rb + r;
          if (rr < CHD){
            P[rr * CHD + cc] = d1[i][j][r];
            P[576 + rr * CHD + cc] = d2[i][j][r];
          }
        }
      }
    }
  #pragma unroll
  for (int tn = 0; tn < 4; tn++)
    #pragma unroll
    for (int rg = 0; rg < 2; rg++){
      int cc = rg * 16 + colb;
      #pragma unroll
      for (int r = 0; r < 4; r++){
        int rr = rg * 16 + rb + r;
        if (rr == cc && rr < CHD) P[1152 + tn * CHD + rr] = nrm[tn][rg][r];
      }
    }
}

// ---------------------------------------------------------------------------
// Kernel 3b: reduce partials over kc -> dots1, dots2, norms (deterministic).
// ---------------------------------------------------------------------------
__global__ __launch_bounds__(256) void reduce_dots(
    const float* __restrict__ dpart,
    float* __restrict__ dots1, float* __restrict__ dots2, float* __restrict__ norms)
{
  const int slot = blockIdx.x * 256 + threadIdx.x;
  const int bh = blockIdx.y;
  if (slot >= 1248) return;
  float s = 0.f;
  #pragma unroll 4
  for (int kc = 0; kc < NKC; kc++)
    s += dpart[((size_t)kc * (NUM_B * NHEADS) + bh) * PSTRIDE + slot];
  if (slot < 576)        dots1[(size_t)bh * 576 + slot] = s;
  else if (slot < 1152)  dots2[(size_t)bh * 576 + (slot - 576)] = s;
  else                   norms[(size_t)bh * 96 + (slot - 1152)] = s;
}

// ---------------------------------------------------------------------------
// Kernel 4: out = gamma1*attn@vx + gamma2*attn@vy, with the cosine-normalize
// + temperature + softmax FUSED in (each block recomputes its (b,h) 24x24
// softmax from dots/norms -- ~1us total redundancy, saves a launch + round-trip).
// ---------------------------------------------------------------------------
__global__ __launch_bounds__(256) void out_kernel(
    const unsigned short* __restrict__ qkv1, const unsigned short* __restrict__ qkv2,
    const float* __restrict__ dots1, const float* __restrict__ dots2,
    const float* __restrict__ norms, const float* __restrict__ temp,
    const float* __restrict__ g1, const float* __restrict__ g2,
    float* __restrict__ out)
{
  __shared__ float A[CHD * CHD];
  const int t = threadIdx.x;
  const int nc = blockIdx.x, hq = blockIdx.y, b = blockIdx.z;
  const int bh = b * NHEADS + hq;
  if (t < CHD){
    const int c = t;
    const float* D1 = dots1 + (size_t)bh * CHD * CHD;
    const float* D2 = dots2 + (size_t)bh * CHD * CHD;
    const float* NB = norms + (size_t)bh * 4 * CHD;
    float n1 = fmaxf(sqrtf(NB[0 * CHD + c]), 1e-12f);
    float n2 = fmaxf(sqrtf(NB[1 * CHD + c]), 1e-12f);
    float T = temp[hq];
    float l[CHD];
    float m = -1e30f;
    #pragma unroll
    for (int dd = 0; dd < CHD; dd++){
      float nx = fmaxf(sqrtf(NB[2 * CHD + dd]), 1e-12f);
      float ny = fmaxf(sqrtf(NB[3 * CHD + dd]), 1e-12f);
      float e = (D1[c * CHD + dd] / (n1 * ny) + D2[c * CHD + dd] / (n2 * nx)) * T;
      l[dd] = e; m = fmaxf(m, e);
    }
    float s = 0.f;
    #pragma unroll
    for (int dd = 0; dd < CHD; dd++){ float p = expf(l[dd] - m); l[dd] = p; s += p; }
    float inv = 1.f / s;
    #pragma unroll
    for (int dd = 0; dd < CHD; dd++) A[c * CHD + dd] = l[dd] * inv;
  }
  __syncthreads();
  const int n = nc * 512 + t * 2;
  const unsigned short* vx = qkv1 + ((size_t)b * NUM_C2 + NUM_C + hq * CHD) * NUM_N + n;
  const unsigned short* vy = qkv2 + ((size_t)b * NUM_C2 + NUM_C + hq * CHD) * NUM_N + n;
  float vxa[CHD], vxb[CHD], vya[CHD], vyb[CHD];
  #pragma unroll
  for (int d = 0; d < CHD; d++){
    unsigned int rx = *(const unsigned int*)(vx + (size_t)d * NUM_N);
    unsigned int ry = *(const unsigned int*)(vy + (size_t)d * NUM_N);
    vxa[d] = bf2f((unsigned short)(rx & 0xffffu));
    vxb[d] = bf2f((unsigned short)(rx >> 16));
    vya[d] = bf2f((unsigned short)(ry & 0xffffu));
    vyb[d] = bf2f((unsigned short)(ry >> 16));
  }
  const float G1 = g1[0], G2 = g2[0];
  float* ob = out + ((size_t)b * NUM_C + hq * CHD) * NUM_N + n;
  #pragma unroll
  for (int cq = 0; cq < CHD; cq++){
    float ax = 0.f, bx = 0.f, ay = 0.f, by = 0.f;
    #pragma unroll
    for (int d = 0; d < CHD; d++){
      float a = A[cq * CHD + d];
      ax += a * vxa[d]; bx += a * vxb[d];
      ay += a * vya[d]; by += a * vyb[d];
    }
    f32x2_t st = {G1 * ax + G2 * ay, G1 * bx + G2 * by};
    *(f32x2_t*)(ob + (size_t)cq * NUM_N) = st;
  }
}

// ---------------------------------------------------------------------------
extern "C" void kernel_launch(void* const* d_in, const int* in_sizes, int n_in,
                              void* d_out, int out_size, void* d_ws, size_t ws_size,
                              hipStream_t stream)
{
  const float* x = (const float*)d_in[0];
  const float* y = (const float*)d_in[1];
  const float* conv_b[3] = {(const float*)d_in[3], (const float*)d_in[7], (const float*)d_in[11]};
  const float* dw_w[3]   = {(const float*)d_in[4], (const float*)d_in[8], (const float*)d_in[12]};
  const float* dw_b[3]   = {(const float*)d_in[5], (const float*)d_in[9], (const float*)d_in[13]};
  const float* conv_w[3] = {(const float*)d_in[2], (const float*)d_in[6], (const float*)d_in[10]};
  const float* temp = (const float*)d_in[14];
  const float* g1 = (const float*)d_in[15];
  const float* g2 = (const float*)d_in[16];
  float* out = (float*)d_out;

  // Workspace (~202.0 MB), phase-aliased (R14-proven):
  //  conv phase:  [xb 24MB @0][yb 24MB @24][z3 144MB @48..192]
  //  gconv order 0,1,2:  qkv0 @0 (xb/yb dead), qkv1 @z3[0], qkv2 @z3[1]
  //  dots:  dpart @z3[2] (21MB, dead after gconv2)
  //  smalls @ 201326592
  char* ws = (char*)d_ws;
  const size_t ZB = (size_t)NUM_B * NUM_C2 * NUM_N * 2;   // 50331648 B
  unsigned short* xb   = (unsigned short*)ws;
  unsigned short* yb   = (unsigned short*)(ws + 25165824);
  unsigned short* z3   = (unsigned short*)(ws + 50331648);  // 3 x ZB
  unsigned short* qkv0 = (unsigned short*)ws;
  unsigned short* qkv1 = (unsigned short*)(ws + 50331648);  // = z3[0]
  unsigned short* qkv2 = (unsigned short*)(ws + 100663296); // = z3[1]
  float* dpart         = (float*)(ws + 150994944);          // = z3[2]
  float* dots1 = (float*)(ws + 201326592);
  float* dots2 = dots1 + NUM_B * NHEADS * CHD * CHD;
  float* norms = dots2 + NUM_B * NHEADS * CHD * CHD;
  unsigned short* Wpk = (unsigned short*)(norms + NUM_B * NHEADS * 4 * CHD);

  // merged input + weight prepack (y==6 lane does weights)
  prepack_all<<<dim3(128, 7, NUM_B), 256, 0, stream>>>(
      x, y, conv_w[0], conv_w[1], conv_w[2], xb, yb, Wpk);

  // all 3 conv branches in ONE dispatch (cross-branch B-tile L2 reuse)
  conv1x1_fused<<<4608, 256, 0, stream>>>(xb, yb, Wpk,
                                          conv_b[0], conv_b[1], conv_b[2], z3);

  dim3 gd(NUM_H / 16, 96, NUM_B), bd(256);
  unsigned short* zb0 = z3;
  unsigned short* zb1 = z3 + ZB / 2;       // shorts
  unsigned short* zb2 = z3 + ZB;           // shorts
  // order matters for aliasing: each gconv writes only dead regions
  gconv4_dw<<<gd, bd, 0, stream>>>(zb0, dw_w[0], dw_b[0], qkv0);
  gconv4_dw<<<gd, bd, 0, stream>>>(zb1, dw_w[1], dw_b[1], qkv1);
  gconv4_dw<<<gd, bd, 0, stream>>>(zb2, dw_w[2], dw_b[2], qkv2);

  dots_kernel<<<dim3(NKC, NHEADS, NUM_B), 64, 0, stream>>>(qkv0, qkv1, qkv2, dpart);
  reduce_dots<<<dim3(5, NUM_B * NHEADS), 256, 0, stream>>>(dpart, dots1, dots2, norms);
  out_kernel<<<dim3(32, NHEADS, NUM_B), 256, 0, stream>>>(
      qkv1, qkv2, dots1, dots2, norms, temp, g1, g2, out);
}

// Round 18
// 232.096 us; speedup vs baseline: 1.1284x; 1.1284x over previous
//
#include <hip/hip_runtime.h>
#include <hip/hip_bf16.h>
#include <stdint.h>

#define NUM_B 4
#define NUM_C 192
#define NUM_C2 384
#define NUM_H 128
#define NUM_W 128
#define NUM_N 16384
#define NHEADS 8
#define CHD 24

#define NKC 128          // K-chunks in dots kernel (R14-proven)
#define PSTRIDE 1280     // partial slots per (kc,bh), 1248 used
#define LROWF 132        // prepack LDS row stride (f32)

typedef float f32x4_t __attribute__((ext_vector_type(4)));
typedef float f32x2_t __attribute__((ext_vector_type(2)));
typedef __bf16 bf16x8_t __attribute__((ext_vector_type(8)));
typedef unsigned short u16x8_t __attribute__((ext_vector_type(8)));
typedef unsigned short u16x4_t __attribute__((ext_vector_type(4)));

__device__ __forceinline__ float bf2f(unsigned short u){
  union { unsigned int i; float f; } v; v.i = ((unsigned int)u) << 16; return v.f;
}
__device__ __forceinline__ unsigned short f2bf(float f){
  union { float f; unsigned int i; } v; v.f = f;
  unsigned int x = v.i;
  x += 0x7fffu + ((x >> 16) & 1u);   // round-to-nearest-even
  return (unsigned short)(x >> 16);
}
__device__ __forceinline__ unsigned short f2bf_n(float f){
  union { __bf16 h; unsigned short u; } cv; cv.h = (__bf16)f; return cv.u;
}

// ---------------------------------------------------------------------------
// Kernel 0: prepack inputs x,y fp32 -> bf16 via LDS transpose (R12-proven),
// MERGED with weight prepack (blockIdx.y == 6; independent outputs -> safe).
// Input layout: [b][nt(128)][s(6)][n(128)][slot(4)][8], slot^((n>>1)&3).
// Weight layout: [br(3)][ot(3)][s(6)][o(128)][slot(4)][8], slot c^((o>>1)&3).
// ---------------------------------------------------------------------------
__global__ __launch_bounds__(256) void prepack_all(
    const float* __restrict__ x, const float* __restrict__ y,
    const float* __restrict__ W0, const float* __restrict__ W1,
    const float* __restrict__ W2,
    unsigned short* __restrict__ xb, unsigned short* __restrict__ yb,
    unsigned short* __restrict__ Wpk)
{
  const int t = threadIdx.x;
  if (blockIdx.y == 6){
    int flat = blockIdx.z * 128 + blockIdx.x;
    if (flat >= 108) return;
    int gtid = flat * 256 + t;           // [0, 27648)
    int br = gtid / 9216;
    int tid = gtid % 9216;
    const float* W = (br == 0) ? W0 : (br == 1) ? W1 : W2;
    unsigned short* o_ = Wpk + (size_t)br * 73728;
    int c = tid & 3;
    int o = (tid >> 2) & 127;
    int s = (tid >> 9) % 6;
    int ot = tid / 3072;
    int sw = c ^ ((o >> 1) & 3);
    const float* src = W + (size_t)(ot * 128 + o) * NUM_C + s * 32 + sw * 8;
    f32x4_t f0 = *(const f32x4_t*)src;
    f32x4_t f1 = *(const f32x4_t*)(src + 4);
    u16x8_t pk;
    pk[0] = f2bf(f0[0]); pk[1] = f2bf(f0[1]); pk[2] = f2bf(f0[2]); pk[3] = f2bf(f0[3]);
    pk[4] = f2bf(f1[0]); pk[5] = f2bf(f1[1]); pk[6] = f2bf(f1[2]); pk[7] = f2bf(f1[3]);
    *(u16x8_t*)(o_ + (size_t)tid * 8) = pk;
    return;
  }
  __shared__ __align__(16) float LX[32 * LROWF];
  __shared__ __align__(16) float LY[32 * LROWF];
  const int nt = blockIdx.x, s = blockIdx.y, b = blockIdx.z;
  const float* px = x + (size_t)b * NUM_C * NUM_N + (size_t)s * 32 * NUM_N + nt * 128;
  const float* py = y + (size_t)b * NUM_C * NUM_N + (size_t)s * 32 * NUM_N + nt * 128;
  #pragma unroll
  for (int i = 0; i < 4; i++){
    int idx = t + 256 * i;
    int k = idx >> 5, n4 = idx & 31;
    f32x4_t vx4 = *(const f32x4_t*)(px + (size_t)k * NUM_N + n4 * 4);
    f32x4_t vy4 = *(const f32x4_t*)(py + (size_t)k * NUM_N + n4 * 4);
    int col = (n4 * 4) ^ ((k >> 3) << 3);
    *(f32x4_t*)(&LX[k * LROWF + col]) = vx4;
    *(f32x4_t*)(&LY[k * LROWF + col]) = vy4;
  }
  __syncthreads();
  size_t obase = ((size_t)(b * 128 + nt) * 6 + s) * 4096;
  #pragma unroll
  for (int i = 0; i < 2; i++){
    int u = t + 256 * i;
    int n = u >> 2, slot = u & 3;
    int c = slot ^ ((n >> 1) & 3);
    int colr = n ^ (c << 3);
    u16x8_t ox, oy;
    #pragma unroll
    for (int kk = 0; kk < 8; kk++){
      ox[kk] = f2bf_n(LX[(c * 8 + kk) * LROWF + colr]);
      oy[kk] = f2bf_n(LY[(c * 8 + kk) * LROWF + colr]);
    }
    *(u16x8_t*)(xb + obase + (size_t)u * 8) = ox;
    *(u16x8_t*)(yb + obase + (size_t)u * 8) = oy;
  }
}

// ---------------------------------------------------------------------------
// Kernel 1: FUSED conv1x1, all 3 branches, one dispatch (R14/R16-proven
// EXACT).  (256,4); depth-1 reg staging (depth-2 spills: R13, R17).
// XCD swizzle: 9 (br x ot) blocks of one (b,nt) share an XCD -> B-tile L2
// hits (FETCH 149->27MB, R9-verified).  z' fragment-native 4-row-interleave.
// ---------------------------------------------------------------------------
__global__ __launch_bounds__(256, 4) void conv1x1_fused(
    const unsigned short* __restrict__ xb, const unsigned short* __restrict__ yb,
    const unsigned short* __restrict__ Wpk,
    const float* __restrict__ b0, const float* __restrict__ b1,
    const float* __restrict__ b2, unsigned short* __restrict__ z3)
{
  __shared__ __align__(16) unsigned short As[2][4096];  // [o(128)][slot(4)][8]
  __shared__ __align__(16) unsigned short Bs[2][4096];  // [n(128)][slot(4)][8]
  const int d = blockIdx.x;
  const int xcd = d & 7;
  const int rest = d >> 3;
  const int j = rest % 9;
  const int m_ = (rest / 9) * 8 + xcd;
  const int br = j / 3;
  const int ot = j % 3;
  const int nt = m_ & 127;
  const int b  = m_ >> 7;
  const int t = threadIdx.x;
  const int lane = t & 63;
  const int wv = t >> 6;
  const int wr = wv >> 1, wc = wv & 1;
  const int n0 = nt * 128;

  const unsigned short* Bp0 = (br == 2) ? yb : xb;
  const unsigned short* Bp1 = yb;                    // only used when br==0
  const int add2 = (br == 0);
  const unsigned short* Wb = Wpk + (size_t)br * 73728;
  const float* bias = (br == 0) ? b0 : (br == 1) ? b1 : b2;
  unsigned short* zout = z3 + (size_t)br * NUM_B * NUM_C2 * NUM_N;

  f32x4_t acc[4][4];
  const f32x4_t zz = {0.f, 0.f, 0.f, 0.f};
  #pragma unroll
  for (int m = 0; m < 4; m++)
    #pragma unroll
    for (int nf = 0; nf < 4; nf++) acc[m][nf] = zz;

  u16x8_t areg[2], breg[2], breg2[2];

  auto loadA = [&](int ks){
    const u16x8_t* gp = (const u16x8_t*)(Wb + (size_t)(ot * 6 + ks) * 4096);
    areg[0] = gp[t];
    areg[1] = gp[t + 256];
  };
  auto loadB = [&](int ks){
    size_t off = ((size_t)(b * 128 + nt) * 6 + ks) * 4096;
    const u16x8_t* gp = (const u16x8_t*)(Bp0 + off);
    breg[0] = gp[t];
    breg[1] = gp[t + 256];
    if (add2){
      const u16x8_t* gp2 = (const u16x8_t*)(Bp1 + off);
      breg2[0] = gp2[t];
      breg2[1] = gp2[t + 256];
    }
  };
  auto writeA = [&](int buf){
    *(u16x8_t*)(&As[buf][(size_t)t * 8]) = areg[0];
    *(u16x8_t*)(&As[buf][(size_t)(t + 256) * 8]) = areg[1];
  };
  auto writeB = [&](int buf){
    if (!add2){
      *(u16x8_t*)(&Bs[buf][(size_t)t * 8]) = breg[0];
      *(u16x8_t*)(&Bs[buf][(size_t)(t + 256) * 8]) = breg[1];
    } else {
      #pragma unroll
      for (int i = 0; i < 2; i++){
        u16x8_t r;
        #pragma unroll
        for (int jj = 0; jj < 8; jj++)
          r[jj] = f2bf_n(bf2f(breg[i][jj]) + bf2f(breg2[i][jj]));
        *(u16x8_t*)(&Bs[buf][(size_t)(t + 256 * i) * 8]) = r;
      }
    }
  };

  auto compute = [&](int buf){
    const int rsel = lane & 15;
    const int g = lane >> 4;
    bf16x8_t af[4], bfr[4];
    #pragma unroll
    for (int m = 0; m < 4; m++){
      int r = wr * 64 + m * 16 + rsel;
      int sw = g ^ ((r >> 1) & 3);
      af[m] = *(const bf16x8_t*)(&As[buf][r * 32 + sw * 8]);
    }
    #pragma unroll
    for (int nf = 0; nf < 4; nf++){
      int r = wc * 64 + nf * 16 + rsel;
      int sw = g ^ ((r >> 1) & 3);
      bfr[nf] = *(const bf16x8_t*)(&Bs[buf][r * 32 + sw * 8]);
    }
    #pragma unroll
    for (int m = 0; m < 4; m++)
      #pragma unroll
      for (int nf = 0; nf < 4; nf++)
        acc[m][nf] = __builtin_amdgcn_mfma_f32_16x16x32_bf16(af[m], bfr[nf], acc[m][nf], 0, 0, 0);
  };

  loadA(0); loadB(0);
  writeA(0); writeB(0);
  __syncthreads();
  int buf = 0;
  #pragma unroll 1
  for (int ks = 0; ks < 6; ks++){
    if (ks < 5){
      loadA(ks + 1);           // global -> regs; vmcnt waits land after compute
      loadB(ks + 1);
    }
    compute(buf);
    if (ks < 5){
      writeA(buf ^ 1);
      writeB(buf ^ 1);
      __syncthreads();
    }
    buf ^= 1;
  }

  // epilogue: fragment-native z' store (R11-proven).
  const int colb = lane & 15;
  const int ob_l = lane >> 4;
  #pragma unroll
  for (int m = 0; m < 4; m++){
    int o_blk = ot * 32 + wr * 16 + m * 4 + ob_l;
    #pragma unroll
    for (int nf = 0; nf < 4; nf++){
      int col = n0 + wc * 64 + nf * 16 + colb;
      u16x4_t pk;
      #pragma unroll
      for (int r = 0; r < 4; r++)
        pk[r] = f2bf_n(acc[m][nf][r] + bias[o_blk * 4 + r]);
      *(u16x4_t*)(zout + (((size_t)b * 96 + o_blk) * NUM_N + col) * 4) = pk;
    }
  }
}

// ---------------------------------------------------------------------------
// Kernel 2: grouped 3x3 conv reading the z' 4-row-interleaved layout.
// ---------------------------------------------------------------------------
__global__ __launch_bounds__(256) void gconv4_dw(
    const unsigned short* __restrict__ zp,
    const float* __restrict__ dww, const float* __restrict__ dwb,
    unsigned short* __restrict__ outq)
{
  const int t = threadIdx.x;
  const int wo = t & 15;
  const int hh = t >> 4;
  const int h = blockIdx.x * 16 + hh;
  const int g2 = blockIdx.y;        // 0..95 = o_blk
  const int b = blockIdx.z;

  float v[4][3][8];
  const unsigned short* src = zp + (size_t)(b * 96 + g2) * NUM_N * 4;
  #pragma unroll
  for (int dy = 0; dy < 3; dy++){
    int row = h + dy - 1;
    if (row >= 0 && row < NUM_H){
      const unsigned short* base = src + (size_t)(row * NUM_W + wo * 8) * 4;
      u16x8_t ch[4];
      #pragma unroll
      for (int q = 0; q < 4; q++) ch[q] = *(const u16x8_t*)(base + q * 8);
      #pragma unroll
      for (int jw = 0; jw < 8; jw++)
        #pragma unroll
        for (int c = 0; c < 4; c++){
          int idx = jw * 4 + c;
          v[c][dy][jw] = bf2f(ch[idx >> 3][idx & 7]);
        }
    } else {
      #pragma unroll
      for (int c = 0; c < 4; c++)
        #pragma unroll
        for (int jw = 0; jw < 8; jw++) v[c][dy][jw] = 0.f;
    }
  }
  float lft[4][3], rgt[4][3];
  #pragma unroll
  for (int c = 0; c < 4; c++)
    #pragma unroll
    for (int dy = 0; dy < 3; dy++){
      float l = __shfl_up(v[c][dy][7], 1u, 64);
      float r = __shfl_down(v[c][dy][0], 1u, 64);
      lft[c][dy] = (wo == 0)  ? 0.f : l;
      rgt[c][dy] = (wo == 15) ? 0.f : r;
    }
  #pragma unroll
  for (int c = 0; c < 4; c++){
    const int oc = g2 * 4 + c;
    const int ci0 = c & 2;
    float wgt[2][9];
    #pragma unroll
    for (int icg = 0; icg < 2; icg++)
      #pragma unroll
      for (int k9 = 0; k9 < 9; k9++)
        wgt[icg][k9] = dww[(size_t)oc * 18 + icg * 9 + k9];
    float bia = dwb[oc];
    u16x8_t st;
    #pragma unroll
    for (int w8 = 0; w8 < 8; w8++){
      float s = bia;
      #pragma unroll
      for (int icg = 0; icg < 2; icg++){
        const int ci = ci0 + icg;
        #pragma unroll
        for (int ky = 0; ky < 3; ky++)
          #pragma unroll
          for (int kx = 0; kx < 3; kx++){
            int wx = w8 + kx - 1;
            float xv = (wx < 0) ? lft[ci][ky] : ((wx > 7) ? rgt[ci][ky] : v[ci][ky][wx]);
            s += wgt[icg][ky * 3 + kx] * xv;
          }
      }
      st[w8] = f2bf(s);
    }
    *(u16x8_t*)(outq + ((size_t)b * NUM_C2 + oc) * NUM_N + h * NUM_W + wo * 8) = st;
  }
}

// ---------------------------------------------------------------------------
// Kernel 3: fused Gram + norms via MFMA.  K split over NKC=128 chunks of 128
// (R14-proven).  Atomic-free plain stores; reduced by reduce_dots.
// ---------------------------------------------------------------------------
__global__ __launch_bounds__(64) void dots_kernel(
    const unsigned short* __restrict__ qkv0, const unsigned short* __restrict__ qkv1,
    const unsigned short* __restrict__ qkv2, float* __restrict__ dpart)
{
  const int lane = threadIdx.x;
  const int kc = blockIdx.x;   // NKC chunks of 128 K-elems
  const int h = blockIdx.y;
  const int b = blockIdx.z;
  const unsigned short* q1 = qkv0 + ((size_t)b * NUM_C2 + h * CHD) * NUM_N;
  const unsigned short* q2 = qkv0 + ((size_t)b * NUM_C2 + NUM_C + h * CHD) * NUM_N;
  const unsigned short* kx = qkv1 + ((size_t)b * NUM_C2 + h * CHD) * NUM_N;
  const unsigned short* ky = qkv2 + ((size_t)b * NUM_C2 + h * CHD) * NUM_N;

  const f32x4_t zz = {0.f, 0.f, 0.f, 0.f};
  f32x4_t d1[2][2], d2[2][2], nrm[4][2];
  #pragma unroll
  for (int i = 0; i < 2; i++)
    #pragma unroll
    for (int j = 0; j < 2; j++){ d1[i][j] = zz; d2[i][j] = zz; }
  #pragma unroll
  for (int tn = 0; tn < 4; tn++){ nrm[tn][0] = zz; nrm[tn][1] = zz; }

  const int row = lane & 15;
  const int kl = (lane >> 4) * 8;
  const int r0 = row;
  const int r1 = (16 + row < CHD) ? (16 + row) : (CHD - 1);   // clamp garbage rows
  #pragma unroll
  for (int ks = 0; ks < 4; ks++){
    const size_t k0 = (size_t)kc * 128 + ks * 32 + kl;
    const size_t off0 = (size_t)r0 * NUM_N + k0;
    const size_t off1 = (size_t)r1 * NUM_N + k0;
    bf16x8_t fq1[2], fq2[2], fkx[2], fky[2];
    fq1[0] = *(const bf16x8_t*)(q1 + off0);  fq1[1] = *(const bf16x8_t*)(q1 + off1);
    fq2[0] = *(const bf16x8_t*)(q2 + off0);  fq2[1] = *(const bf16x8_t*)(q2 + off1);
    fkx[0] = *(const bf16x8_t*)(kx + off0);  fkx[1] = *(const bf16x8_t*)(kx + off1);
    fky[0] = *(const bf16x8_t*)(ky + off0);  fky[1] = *(const bf16x8_t*)(ky + off1);
    #pragma unroll
    for (int i = 0; i < 2; i++)
      #pragma unroll
      for (int j = 0; j < 2; j++){
        d1[i][j] = __builtin_amdgcn_mfma_f32_16x16x32_bf16(fq1[i], fky[j], d1[i][j], 0, 0, 0);
        d2[i][j] = __builtin_amdgcn_mfma_f32_16x16x32_bf16(fq2[i], fkx[j], d2[i][j], 0, 0, 0);
      }
    #pragma unroll
    for (int rg = 0; rg < 2; rg++){
      nrm[0][rg] = __builtin_amdgcn_mfma_f32_16x16x32_bf16(fq1[rg], fq1[rg], nrm[0][rg], 0, 0, 0);
      nrm[1][rg] = __builtin_amdgcn_mfma_f32_16x16x32_bf16(fq2[rg], fq2[rg], nrm[1][rg], 0, 0, 0);
      nrm[2][rg] = __builtin_amdgcn_mfma_f32_16x16x32_bf16(fkx[rg], fkx[rg], nrm[2][rg], 0, 0, 0);
      nrm[3][rg] = __builtin_amdgcn_mfma_f32_16x16x32_bf16(fky[rg], fky[rg], nrm[3][rg], 0, 0, 0);
    }
  }

  float* P = dpart + ((size_t)kc * (NUM_B * NHEADS) + (b * NHEADS + h)) * PSTRIDE;
  const int colb = lane & 15;
  const int rb = (lane >> 4) * 4;
  #pragma unroll
  for (int i = 0; i < 2; i++)
    #pragma unroll
    for (int j = 0; j < 2; j++){
      int cc = j * 16 + colb;
      if (cc < CHD){
        #pragma unroll
        for (int r = 0; r < 4; r++){
          int rr = i * 16 + rb + r;
          if (rr < CHD){
            P[rr * CHD + cc] = d1[i][j][r];
            P[576 + rr * CHD + cc] = d2[i][j][r];
          }
        }
      }
    }
  #pragma unroll
  for (int tn = 0; tn < 4; tn++)
    #pragma unroll
    for (int rg = 0; rg < 2; rg++){
      int cc = rg * 16 + colb;
      #pragma unroll
      for (int r = 0; r < 4; r++){
        int rr = rg * 16 + rb + r;
        if (rr == cc && rr < CHD) P[1152 + tn * CHD + rr] = nrm[tn][rg][r];
      }
    }
}

// ---------------------------------------------------------------------------
// Kernel 3b: reduce partials over kc -> dots1, dots2, norms (deterministic).
// ---------------------------------------------------------------------------
__global__ __launch_bounds__(256) void reduce_dots(
    const float* __restrict__ dpart,
    float* __restrict__ dots1, float* __restrict__ dots2, float* __restrict__ norms)
{
  const int slot = blockIdx.x * 256 + threadIdx.x;
  const int bh = blockIdx.y;
  if (slot >= 1248) return;
  float s = 0.f;
  #pragma unroll 4
  for (int kc = 0; kc < NKC; kc++)
    s += dpart[((size_t)kc * (NUM_B * NHEADS) + bh) * PSTRIDE + slot];
  if (slot < 576)        dots1[(size_t)bh * 576 + slot] = s;
  else if (slot < 1152)  dots2[(size_t)bh * 576 + (slot - 576)] = s;
  else                   norms[(size_t)bh * 96 + (slot - 1152)] = s;
}

// ---------------------------------------------------------------------------
// Kernel 4: out = gamma1*attn@vx + gamma2*attn@vy, with the cosine-normalize
// + temperature + softmax FUSED in (each block recomputes its (b,h) 24x24
// softmax from dots/norms — ~1us total redundancy, saves a launch).
// ---------------------------------------------------------------------------
__global__ __launch_bounds__(256) void out_kernel(
    const unsigned short* __restrict__ qkv1, const unsigned short* __restrict__ qkv2,
    const float* __restrict__ dots1, const float* __restrict__ dots2,
    const float* __restrict__ norms, const float* __restrict__ temp,
    const float* __restrict__ g1, const float* __restrict__ g2,
    float* __restrict__ out)
{
  __shared__ float A[CHD * CHD];
  const int t = threadIdx.x;
  const int nc = blockIdx.x, hq = blockIdx.y, b = blockIdx.z;
  const int bh = b * NHEADS + hq;
  if (t < CHD){
    const int c = t;
    const float* D1 = dots1 + (size_t)bh * CHD * CHD;
    const float* D2 = dots2 + (size_t)bh * CHD * CHD;
    const float* NB = norms + (size_t)bh * 4 * CHD;
    float n1 = fmaxf(sqrtf(NB[0 * CHD + c]), 1e-12f);
    float n2 = fmaxf(sqrtf(NB[1 * CHD + c]), 1e-12f);
    float T = temp[hq];
    float l[CHD];
    float m = -1e30f;
    #pragma unroll
    for (int dd = 0; dd < CHD; dd++){
      float nx = fmaxf(sqrtf(NB[2 * CHD + dd]), 1e-12f);
      float ny = fmaxf(sqrtf(NB[3 * CHD + dd]), 1e-12f);
      float e = (D1[c * CHD + dd] / (n1 * ny) + D2[c * CHD + dd] / (n2 * nx)) * T;
      l[dd] = e; m = fmaxf(m, e);
    }
    float s = 0.f;
    #pragma unroll
    for (int dd = 0; dd < CHD; dd++){ float p = expf(l[dd] - m); l[dd] = p; s += p; }
    float inv = 1.f / s;
    #pragma unroll
    for (int dd = 0; dd < CHD; dd++) A[c * CHD + dd] = l[dd] * inv;
  }
  __syncthreads();
  const int n = nc * 512 + t * 2;
  const unsigned short* vx = qkv1 + ((size_t)b * NUM_C2 + NUM_C + hq * CHD) * NUM_N + n;
  const unsigned short* vy = qkv2 + ((size_t)b * NUM_C2 + NUM_C + hq * CHD) * NUM_N + n;
  float vxa[CHD], vxb[CHD], vya[CHD], vyb[CHD];
  #pragma unroll
  for (int d = 0; d < CHD; d++){
    unsigned int rx = *(const unsigned int*)(vx + (size_t)d * NUM_N);
    unsigned int ry = *(const unsigned int*)(vy + (size_t)d * NUM_N);
    vxa[d] = bf2f((unsigned short)(rx & 0xffffu));
    vxb[d] = bf2f((unsigned short)(rx >> 16));
    vya[d] = bf2f((unsigned short)(ry & 0xffffu));
    vyb[d] = bf2f((unsigned short)(ry >> 16));
  }
  const float G1 = g1[0], G2 = g2[0];
  float* ob = out + ((size_t)b * NUM_C + hq * CHD) * NUM_N + n;
  #pragma unroll
  for (int cq = 0; cq < CHD; cq++){
    float ax = 0.f, bx = 0.f, ay = 0.f, by = 0.f;
    #pragma unroll
    for (int d = 0; d < CHD; d++){
      float a = A[cq * CHD + d];
      ax += a * vxa[d]; bx += a * vxb[d];
      ay += a * vya[d]; by += a * vyb[d];
    }
    f32x2_t st = {G1 * ax + G2 * ay, G1 * bx + G2 * by};
    *(f32x2_t*)(ob + (size_t)cq * NUM_N) = st;
  }
}

// ---------------------------------------------------------------------------
extern "C" void kernel_launch(void* const* d_in, const int* in_sizes, int n_in,
                              void* d_out, int out_size, void* d_ws, size_t ws_size,
                              hipStream_t stream)
{
  const float* x = (const float*)d_in[0];
  const float* y = (const float*)d_in[1];
  const float* conv_b[3] = {(const float*)d_in[3], (const float*)d_in[7], (const float*)d_in[11]};
  const float* dw_w[3]   = {(const float*)d_in[4], (const float*)d_in[8], (const float*)d_in[12]};
  const float* dw_b[3]   = {(const float*)d_in[5], (const float*)d_in[9], (const float*)d_in[13]};
  const float* conv_w[3] = {(const float*)d_in[2], (const float*)d_in[6], (const float*)d_in[10]};
  const float* temp = (const float*)d_in[14];
  const float* g1 = (const float*)d_in[15];
  const float* g2 = (const float*)d_in[16];
  float* out = (float*)d_out;

  // Workspace (~202.0 MB), phase-aliased (R14-proven):
  //  conv phase:  [xb 24MB @0][yb 24MB @24][z3 144MB @48..192]
  //  gconv order 0,1,2:  qkv0 @0 (xb/yb dead), qkv1 @z3[0], qkv2 @z3[1]
  //  dots:  dpart @z3[2] (21MB, dead after gconv2)
  //  smalls @ 201326592
  char* ws = (char*)d_ws;
  const size_t ZB = (size_t)NUM_B * NUM_C2 * NUM_N * 2;   // 50331648 B
  unsigned short* xb   = (unsigned short*)ws;
  unsigned short* yb   = (unsigned short*)(ws + 25165824);
  unsigned short* z3   = (unsigned short*)(ws + 50331648);  // 3 x ZB
  unsigned short* qkv0 = (unsigned short*)ws;
  unsigned short* qkv1 = (unsigned short*)(ws + 50331648);  // = z3[0]
  unsigned short* qkv2 = (unsigned short*)(ws + 100663296); // = z3[1]
  float* dpart         = (float*)(ws + 150994944);          // = z3[2]
  float* dots1 = (float*)(ws + 201326592);
  float* dots2 = dots1 + NUM_B * NHEADS * CHD * CHD;
  float* norms = dots2 + NUM_B * NHEADS * CHD * CHD;
  unsigned short* Wpk = (unsigned short*)(norms + NUM_B * NHEADS * 4 * CHD);

  // merged input + weight prepack (y==6 lane does weights)
  prepack_all<<<dim3(128, 7, NUM_B), 256, 0, stream>>>(
      x, y, conv_w[0], conv_w[1], conv_w[2], xb, yb, Wpk);

  // all 3 conv branches in ONE dispatch (cross-branch B-tile L2 reuse)
  conv1x1_fused<<<4608, 256, 0, stream>>>(xb, yb, Wpk,
                                          conv_b[0], conv_b[1], conv_b[2], z3);

  dim3 gd(NUM_H / 16, 96, NUM_B), bd(256);
  unsigned short* zb0 = z3;
  unsigned short* zb1 = z3 + ZB / 2;       // shorts
  unsigned short* zb2 = z3 + ZB;           // shorts
  // order matters for aliasing: each gconv writes only dead regions
  gconv4_dw<<<gd, bd, 0, stream>>>(zb0, dw_w[0], dw_b[0], qkv0);
  gconv4_dw<<<gd, bd, 0, stream>>>(zb1, dw_w[1], dw_b[1], qkv1);
  gconv4_dw<<<gd, bd, 0, stream>>>(zb2, dw_w[2], dw_b[2], qkv2);

  dots_kernel<<<dim3(NKC, NHEADS, NUM_B), 64, 0, stream>>>(qkv0, qkv1, qkv2, dpart);
  reduce_dots<<<dim3(5, NUM_B * NHEADS), 256, 0, stream>>>(dpart, dots1, dots2, norms);
  out_kernel<<<dim3(32, NHEADS, NUM_B), 256, 0, stream>>>(
      qkv1, qkv2, dots1, dots2, norms, temp, g1, g2, out);
}